// Round 10
// baseline (213.151 us; speedup 1.0000x reference)
//
#include <hip/hip_runtime.h>

// MHA forward, B=2, S=2048, D=1024, H=16, K=64, fp32 in/out, bf16 MFMA internally.
// R10: triple-buffered K-loops everywhere -> ONE barrier per iteration (the second
// barrier in a 2-buffer loop only protects the buffer being overwritten; with 3
// buffers, the iteration-entry barrier already proves tile it-1 is consumed).
// Staging issued right after the barrier for max DMA lead. Math unchanged from R9.

#define NH 16
#define KS 64
#define DM 1024
#define BB 2
#define SS 2048
#define NT (BB*SS)   // 4096 tokens
#define HKD 1024     // NH*KS
#define L2E 1.44269504088896340736f

typedef __attribute__((ext_vector_type(4))) float floatx4;
typedef __attribute__((ext_vector_type(8))) short short8;

#define BAR() asm volatile("s_barrier" ::: "memory")

__device__ __forceinline__ unsigned short f2b(float f) {
  unsigned u = __builtin_bit_cast(unsigned, f);
  u = (u + 0x7fffu + ((u >> 16) & 1u)) >> 16;
  return (unsigned short)u;
}

__device__ __forceinline__ floatx4 mfma16(short8 a, short8 b, floatx4 c) {
  return __builtin_amdgcn_mfma_f32_16x16x32_bf16(a, b, c, 0, 0, 0);
}

// async global->LDS, 16B per lane. LDS dest must be wave-uniform base + lane*16.
__device__ __forceinline__ void async16(const void* g, void* l) {
  __builtin_amdgcn_global_load_lds(
      (const __attribute__((address_space(1))) unsigned int*)g,
      (__attribute__((address_space(3))) unsigned int*)l, 16, 0, 0);
}

// ------ prep: cast x (f32->bf16) + transpose+cast all W, one launch ------
__global__ __launch_bounds__(256) void prep_kernel(
    const float* __restrict__ x,
    const float* __restrict__ Wq, const float* __restrict__ Wk,
    const float* __restrict__ Wv, const float* __restrict__ Wo,
    unsigned short* __restrict__ xb,
    unsigned short* __restrict__ wqt, unsigned short* __restrict__ wkt,
    unsigned short* __restrict__ wvt, unsigned short* __restrict__ wot) {
  int bid = blockIdx.x;
  if (bid < NT * DM / 1024) {
    int i = (bid * 256 + threadIdx.x) * 4;
    float4 v = *(const float4*)(x + i);
    ushort4 o;
    o.x = f2b(v.x); o.y = f2b(v.y); o.z = f2b(v.z); o.w = f2b(v.w);
    *(ushort4*)(xb + i) = o;
    return;
  }
  int b2 = bid - NT * DM / 1024;
  int z = b2 >> 8;
  const float* W; unsigned short* Wt;
  if (z == 0)      { W = Wq; Wt = wqt; }
  else if (z == 1) { W = Wk; Wt = wkt; }
  else if (z == 2) { W = Wv; Wt = wvt; }
  else             { W = Wo; Wt = wot; }
  __shared__ __align__(16) unsigned short tile[64][80];
  int k0 = (b2 & 15) * 64, n0 = ((b2 >> 4) & 15) * 64;
  int t = threadIdx.x;
  int c0 = (t & 15) * 4, r = t >> 4;
  #pragma unroll
  for (int p = 0; p < 4; ++p) {
    int rr = r + p * 16;
    float4 v = *(const float4*)(W + (k0 + rr) * DM + n0 + c0);
    tile[c0 + 0][rr] = f2b(v.x);
    tile[c0 + 1][rr] = f2b(v.y);
    tile[c0 + 2][rr] = f2b(v.z);
    tile[c0 + 3][rr] = f2b(v.w);
  }
  __syncthreads();
  int cc0 = (t & 7) * 8, rn = t >> 3;
  #pragma unroll
  for (int p = 0; p < 2; ++p) {
    int nn = rn + p * 32;
    *(short8*)(Wt + (n0 + nn) * DM + k0 + cc0) = *(const short8*)(&tile[nn][cc0]);
  }
}

// ---- QKV GEMM: 128x128 tile, 4 waves, BK=32 triple-buffer, 1 barrier/iter ----
__global__ __launch_bounds__(256) void gemm_qkv_kernel(
    const unsigned short* __restrict__ xb,
    const unsigned short* __restrict__ wqt, const unsigned short* __restrict__ wkt,
    const unsigned short* __restrict__ wvt,
    const float* __restrict__ bq, const float* __restrict__ bk, const float* __restrict__ bv,
    unsigned short* __restrict__ qb, unsigned short* __restrict__ kbuf,
    unsigned short* __restrict__ vt) {
  // A bufs at [b*4096], B bufs at [12288 + b*4096] (shorts); 48 KB total.
  // Epilogue V-transpose reuses the same region (4 x 4608 shorts = 36 KB).
  __shared__ __align__(16) unsigned short smem[24576];
  const unsigned short* Bt; const float* bias; float scale; int zid = blockIdx.z;
  if (zid == 0)      { Bt = wqt; bias = bq; scale = 0.125f * L2E; }
  else if (zid == 1) { Bt = wkt; bias = bk; scale = 1.0f; }
  else               { Bt = wvt; bias = bv; scale = 1.0f; }
  int m0 = blockIdx.x * 128, n0 = blockIdx.y * 128;
  int t = threadIdx.x, w = t >> 6, lane = t & 63, cl = lane & 15, quad = lane >> 4;
  int wr = (w >> 1) * 64, wc = (w & 1) * 64;
  floatx4 acc[4][4];
  #pragma unroll
  for (int i = 0; i < 4; ++i)
    #pragma unroll
    for (int j = 0; j < 4; ++j)
      acc[i][j] = floatx4{0.f, 0.f, 0.f, 0.f};

  auto stage = [&](int kc, int buf) {
    #pragma unroll
    for (int i = 0; i < 2; ++i) {
      int c = i * 256 + t;
      int row = c >> 2, col = (c & 3) ^ (row & 3);
      async16(xb + (m0 + row) * DM + kc * 32 + col * 8, &smem[buf * 4096 + c * 8]);
      async16(Bt + (n0 + row) * DM + kc * 32 + col * 8, &smem[12288 + buf * 4096 + c * 8]);
    }
  };
  stage(0, 0);
  stage(1, 1);

  const int NK = DM / 32;
  for (int kc = 0; kc < NK; ++kc) {
    int cur = kc % 3;
    if (kc < NK - 1) asm volatile("s_waitcnt vmcnt(4)" ::: "memory");
    else             asm volatile("s_waitcnt vmcnt(0)" ::: "memory");
    BAR();
    if (kc + 2 < NK) stage(kc + 2, (kc + 2) % 3);
    const unsigned short* Ac = &smem[cur * 4096];
    const unsigned short* Bc = &smem[12288 + cur * 4096];
    short8 a[4], b[4];
    #pragma unroll
    for (int i = 0; i < 4; ++i)
      a[i] = *(const short8*)&Ac[(wr + i * 16 + cl) * 32 + ((quad ^ (cl & 3)) * 8)];
    #pragma unroll
    for (int j = 0; j < 4; ++j)
      b[j] = *(const short8*)&Bc[(wc + j * 16 + cl) * 32 + ((quad ^ (cl & 3)) * 8)];
    #pragma unroll
    for (int i = 0; i < 4; ++i)
      #pragma unroll
      for (int j = 0; j < 4; ++j)
        acc[i][j] = mfma16(a[i], b[j], acc[i][j]);
  }
  __syncthreads(); // all waves done with staging LDS before epilogue reuse

  int h = (n0 + wc) >> 6;
  if (zid < 2) {
    unsigned short* dst = (zid == 0) ? qb : kbuf;
    #pragma unroll
    for (int j = 0; j < 4; ++j) {
      float bj = bias[n0 + wc + j * 16 + cl];
      int kd = j * 16 + cl;
      #pragma unroll
      for (int i = 0; i < 4; ++i)
        #pragma unroll
        for (int r = 0; r < 4; ++r) {
          int token = m0 + wr + i * 16 + quad * 4 + r;
          int bz = token >> 11, s = token & (SS - 1);
          float val = (acc[i][j][r] + bj) * scale;
          dst[(((bz * NH + h) * SS + s) << 6) + kd] = f2b(val);
        }
    }
  } else {
    unsigned short* tr = &smem[w * 4608];
    #pragma unroll
    for (int j = 0; j < 4; ++j) {
      float bj = bias[n0 + wc + j * 16 + cl];
      #pragma unroll
      for (int i = 0; i < 4; ++i) {
        unsigned short b0 = f2b(acc[i][j][0] + bj), b1 = f2b(acc[i][j][1] + bj);
        unsigned short b2 = f2b(acc[i][j][2] + bj), b3 = f2b(acc[i][j][3] + bj);
        uint2 pk;
        pk.x = (unsigned)b0 | ((unsigned)b1 << 16);
        pk.y = (unsigned)b2 | ((unsigned)b3 << 16);
        *(uint2*)&tr[(j * 16 + cl) * 72 + i * 16 + quad * 4] = pk;
      }
    }
    asm volatile("s_waitcnt lgkmcnt(0)" ::: "memory");
    int tokbase = m0 + wr;
    int bz = tokbase >> 11, s0 = tokbase & (SS - 1);
    unsigned short* vdst = vt + (((bz * NH + h) * KS) * SS) + s0;
    #pragma unroll
    for (int p = 0; p < 8; ++p) {
      int row = p * 8 + (lane >> 3);
      int tk = (lane & 7) * 8;
      short8 vv = *(const short8*)&tr[row * 72 + tk];
      *(short8*)(vdst + row * SS + tk) = vv;
    }
  }
}

// ---- attention: 8 waves x 16 q-rows, S^T/O^T, triple-buffer K/V, 1 barrier/iter ----
// l via ones-MFMA on the same P^T fragments (consistent by construction).
__global__ __launch_bounds__(512) void attn_kernel(
    const unsigned short* __restrict__ Q, const unsigned short* __restrict__ Kb,
    const unsigned short* __restrict__ Vt, unsigned short* __restrict__ AO) {
  __shared__ __align__(16) unsigned short Ks[3][4096], Vs[3][4096]; // 48 KB triple buf
  __shared__ __align__(16) unsigned short Ps[8][1024];              // per-wave P^T (16 KB)
  int t = threadIdx.x, w = t >> 6, lane = t & 63, cl = lane & 15, quad = lane >> 4;
  int clm = cl & 7;
  int h = blockIdx.y, bz = blockIdx.z, bh = bz * NH + h;
  int q0 = blockIdx.x * 128 + w * 16;
  const unsigned short* Qp = Q + (bh * SS + q0) * KS;
  const unsigned short* Kp = Kb + bh * SS * KS;
  const unsigned short* Vp = Vt + bh * KS * SS;
  unsigned short* p_w = Ps[w];

  short8 qa[2];
  #pragma unroll
  for (int c = 0; c < 2; ++c)
    qa[c] = *(const short8*)(Qp + cl * KS + c * 32 + quad * 8);

  short8 ones;
  #pragma unroll
  for (int j = 0; j < 8; ++j) ones[j] = (short)0x3f80; // bf16 1.0

  floatx4 lacc = {0.f, 0.f, 0.f, 0.f};
  floatx4 oa[4];
  #pragma unroll
  for (int j = 0; j < 4; ++j) oa[j] = floatx4{0.f, 0.f, 0.f, 0.f};

  auto stage = [&](int tile, int buf) {
    int row = t >> 3, col8 = (t & 7) ^ (row & 7);
    async16(Kp + (tile * 64 + row) * KS + col8 * 8, &Ks[buf][t * 8]);
    async16(Vp + row * SS + tile * 64 + col8 * 8, &Vs[buf][t * 8]);
  };
  stage(0, 0);
  stage(1, 1);

  const int NTILES = SS / 64;
  for (int it = 0; it < NTILES; ++it) {
    int cur = it % 3;
    if (it < NTILES - 1) asm volatile("s_waitcnt vmcnt(2)" ::: "memory");
    else                 asm volatile("s_waitcnt vmcnt(0)" ::: "memory");
    BAR();
    if (it + 2 < NTILES) stage(it + 2, (it + 2) % 3);

    floatx4 s[4];
    #pragma unroll
    for (int kt = 0; kt < 4; ++kt) {
      short8 kb0 = *(const short8*)&Ks[cur][(kt * 16 + cl) * 64 + ((quad ^ clm) * 8)];
      short8 kb1 = *(const short8*)&Ks[cur][(kt * 16 + cl) * 64 + (((4 + quad) ^ clm) * 8)];
      floatx4 z = {0.f, 0.f, 0.f, 0.f};
      s[kt] = mfma16(kb1, qa[1], mfma16(kb0, qa[0], z));
    }
    #pragma unroll
    for (int kt = 0; kt < 4; ++kt) {
      unsigned u[4];
      #pragma unroll
      for (int r = 0; r < 4; ++r)
        u[r] = __builtin_bit_cast(unsigned, __builtin_amdgcn_exp2f(s[kt][r]));
      uint2 pk;
      pk.x = __builtin_amdgcn_perm(u[1], u[0], 0x07060302);
      pk.y = __builtin_amdgcn_perm(u[3], u[2], 0x07060302);
      int off = cl * 64 + (((kt * 2 + (quad >> 1)) ^ clm) * 8) + (quad & 1) * 4;
      *(uint2*)(p_w + off) = pk;
    }
    asm volatile("s_waitcnt lgkmcnt(0)" ::: "memory");
    short8 pa[2];
    #pragma unroll
    for (int c = 0; c < 2; ++c)
      pa[c] = *(const short8*)(p_w + cl * 64 + (((c * 4 + quad) ^ clm) * 8));
    lacc = mfma16(ones, pa[1], mfma16(ones, pa[0], lacc));
    #pragma unroll
    for (int j = 0; j < 4; ++j) {
      short8 vb0 = *(const short8*)&Vs[cur][(j * 16 + cl) * 64 + ((quad ^ clm) * 8)];
      short8 vb1 = *(const short8*)&Vs[cur][(j * 16 + cl) * 64 + (((4 + quad) ^ clm) * 8)];
      oa[j] = mfma16(vb1, pa[1], mfma16(vb0, pa[0], oa[j]));
    }
  }

  float inv = 1.0f / lacc[0];
  unsigned short* aop = AO + (bz * SS + q0 + cl) * DM + h * KS + quad * 4;
  #pragma unroll
  for (int j = 0; j < 4; ++j) {
    unsigned short b0 = f2b(oa[j][0] * inv), b1 = f2b(oa[j][1] * inv);
    unsigned short b2 = f2b(oa[j][2] * inv), b3 = f2b(oa[j][3] * inv);
    uint2 pk;
    pk.x = (unsigned)b0 | ((unsigned)b1 << 16);
    pk.y = (unsigned)b2 | ((unsigned)b3 << 16);
    *(uint2*)(aop + j * 16) = pk;
  }
}

// ---- output GEMM: 256x64 tile, 4 waves, BK=32 triple-buffer, 1 barrier/iter ----
__global__ __launch_bounds__(256) void gemm_out_kernel(
    const unsigned short* __restrict__ ao, const unsigned short* __restrict__ wot,
    const float* __restrict__ bo, float* __restrict__ out) {
  __shared__ __align__(16) unsigned short As[3][8192], Bs[3][2048]; // 60 KB
  int m0 = blockIdx.x * 256, n0 = blockIdx.y * 64;
  int t = threadIdx.x, w = t >> 6, lane = t & 63, cl = lane & 15, quad = lane >> 4;
  int wr = w * 64;
  floatx4 acc[4][4];
  #pragma unroll
  for (int i = 0; i < 4; ++i)
    #pragma unroll
    for (int j = 0; j < 4; ++j)
      acc[i][j] = floatx4{0.f, 0.f, 0.f, 0.f};

  auto stage = [&](int kc, int buf) {
    #pragma unroll
    for (int i = 0; i < 4; ++i) {
      int c = i * 256 + t;
      int row = c >> 2, col = (c & 3) ^ (row & 3);
      async16(ao + (m0 + row) * HKD + kc * 32 + col * 8, &As[buf][c * 8]);
    }
    {
      int c = t;
      int row = c >> 2, col = (c & 3) ^ (row & 3);
      async16(wot + (n0 + row) * HKD + kc * 32 + col * 8, &Bs[buf][c * 8]);
    }
  };
  stage(0, 0);
  stage(1, 1);

  const int NK = HKD / 32;
  for (int kc = 0; kc < NK; ++kc) {
    int cur = kc % 3;
    if (kc < NK - 1) asm volatile("s_waitcnt vmcnt(5)" ::: "memory");
    else             asm volatile("s_waitcnt vmcnt(0)" ::: "memory");
    BAR();
    if (kc + 2 < NK) stage(kc + 2, (kc + 2) % 3);
    short8 a[4], b[4];
    #pragma unroll
    for (int i = 0; i < 4; ++i)
      a[i] = *(const short8*)&As[cur][(wr + i * 16 + cl) * 32 + ((quad ^ (cl & 3)) * 8)];
    #pragma unroll
    for (int j = 0; j < 4; ++j)
      b[j] = *(const short8*)&Bs[cur][(j * 16 + cl) * 32 + ((quad ^ (cl & 3)) * 8)];
    #pragma unroll
    for (int i = 0; i < 4; ++i)
      #pragma unroll
      for (int j = 0; j < 4; ++j)
        acc[i][j] = mfma16(a[i], b[j], acc[i][j]);
  }
  #pragma unroll
  for (int j = 0; j < 4; ++j) {
    float bj = bo[n0 + j * 16 + cl];
    #pragma unroll
    for (int i = 0; i < 4; ++i)
      #pragma unroll
      for (int r = 0; r < 4; ++r) {
        int token = m0 + wr + i * 16 + quad * 4 + r;
        out[token * DM + n0 + j * 16 + cl] = acc[i][j][r] + bj;
      }
  }
}

extern "C" void kernel_launch(void* const* d_in, const int* in_sizes, int n_in,
                              void* d_out, int out_size, void* d_ws, size_t ws_size,
                              hipStream_t stream) {
  const float* x  = (const float*)d_in[0];
  const float* Wq = (const float*)d_in[1];
  const float* bq = (const float*)d_in[2];
  const float* Wk = (const float*)d_in[3];
  const float* bk = (const float*)d_in[4];
  const float* Wv = (const float*)d_in[5];
  const float* bv = (const float*)d_in[6];
  const float* Wo = (const float*)d_in[7];
  const float* bo = (const float*)d_in[8];
  float* out = (float*)d_out;
  char* ws = (char*)d_ws;
  unsigned short* xb  = (unsigned short*)(ws);                       // 8 MiB
  unsigned short* wqt = (unsigned short*)(ws + (8ull  << 20));       // 2 MiB
  unsigned short* wkt = (unsigned short*)(ws + (10ull << 20));       // 2 MiB
  unsigned short* wvt = (unsigned short*)(ws + (12ull << 20));       // 2 MiB
  unsigned short* wot = (unsigned short*)(ws + (14ull << 20));       // 2 MiB
  unsigned short* qb  = (unsigned short*)(ws + (16ull << 20));       // 8 MiB
  unsigned short* kbf = (unsigned short*)(ws + (24ull << 20));       // 8 MiB
  unsigned short* vt  = (unsigned short*)(ws + (40ull << 20));       // 8 MiB
  unsigned short* ao  = (unsigned short*)(ws + (48ull << 20));       // 8 MiB

  hipLaunchKernelGGL(prep_kernel, dim3(NT * DM / 1024 + 1024), dim3(256), 0, stream,
                     x, Wq, Wk, Wv, Wo, xb, wqt, wkt, wvt, wot);
  hipLaunchKernelGGL(gemm_qkv_kernel, dim3(NT / 128, HKD / 128, 3), dim3(256), 0, stream,
                     xb, wqt, wkt, wvt, bq, bk, bv, qb, kbf, vt);
  hipLaunchKernelGGL(attn_kernel, dim3(SS / 128, NH, BB), dim3(512), 0, stream, qb, kbf, vt, ao);
  hipLaunchKernelGGL(gemm_out_kernel, dim3(NT / 256, DM / 64), dim3(256), 0, stream, ao, wot, bo, out);
}

// Round 11
// 202.216 us; speedup vs baseline: 1.0541x; 1.0541x over previous
//
#include <hip/hip_runtime.h>

// MHA forward, B=2, S=2048, D=1024, H=16, K=64, fp32 in/out, bf16 MFMA internally.
// R11: revert R10's triple-buffer (regressed). Attention: 4 waves x 32 q-rows/wave
// (two Q B-fragments per wave) — halves per-work K/V LDS read traffic (the measured
// limiter: 18 ds_read_b128/iter/wave ~ 2.6 GB total ~ 37 us at LDS ceiling).
// GEMMs identical to R9 (2-buffer, 2 raw barriers, vmcnt prefetch).

#define NH 16
#define KS 64
#define DM 1024
#define BB 2
#define SS 2048
#define NT (BB*SS)   // 4096 tokens
#define HKD 1024     // NH*KS
#define L2E 1.44269504088896340736f

typedef __attribute__((ext_vector_type(4))) float floatx4;
typedef __attribute__((ext_vector_type(8))) short short8;

#define BAR() asm volatile("s_barrier" ::: "memory")

__device__ __forceinline__ unsigned short f2b(float f) {
  unsigned u = __builtin_bit_cast(unsigned, f);
  u = (u + 0x7fffu + ((u >> 16) & 1u)) >> 16;
  return (unsigned short)u;
}

__device__ __forceinline__ floatx4 mfma16(short8 a, short8 b, floatx4 c) {
  return __builtin_amdgcn_mfma_f32_16x16x32_bf16(a, b, c, 0, 0, 0);
}

// async global->LDS, 16B per lane. LDS dest must be wave-uniform base + lane*16.
__device__ __forceinline__ void async16(const void* g, void* l) {
  __builtin_amdgcn_global_load_lds(
      (const __attribute__((address_space(1))) unsigned int*)g,
      (__attribute__((address_space(3))) unsigned int*)l, 16, 0, 0);
}

// ------ prep: cast x (f32->bf16) + transpose+cast all W, one launch ------
__global__ __launch_bounds__(256) void prep_kernel(
    const float* __restrict__ x,
    const float* __restrict__ Wq, const float* __restrict__ Wk,
    const float* __restrict__ Wv, const float* __restrict__ Wo,
    unsigned short* __restrict__ xb,
    unsigned short* __restrict__ wqt, unsigned short* __restrict__ wkt,
    unsigned short* __restrict__ wvt, unsigned short* __restrict__ wot) {
  int bid = blockIdx.x;
  if (bid < NT * DM / 1024) {
    int i = (bid * 256 + threadIdx.x) * 4;
    float4 v = *(const float4*)(x + i);
    ushort4 o;
    o.x = f2b(v.x); o.y = f2b(v.y); o.z = f2b(v.z); o.w = f2b(v.w);
    *(ushort4*)(xb + i) = o;
    return;
  }
  int b2 = bid - NT * DM / 1024;
  int z = b2 >> 8;
  const float* W; unsigned short* Wt;
  if (z == 0)      { W = Wq; Wt = wqt; }
  else if (z == 1) { W = Wk; Wt = wkt; }
  else if (z == 2) { W = Wv; Wt = wvt; }
  else             { W = Wo; Wt = wot; }
  __shared__ __align__(16) unsigned short tile[64][80];
  int k0 = (b2 & 15) * 64, n0 = ((b2 >> 4) & 15) * 64;
  int t = threadIdx.x;
  int c0 = (t & 15) * 4, r = t >> 4;
  #pragma unroll
  for (int p = 0; p < 4; ++p) {
    int rr = r + p * 16;
    float4 v = *(const float4*)(W + (k0 + rr) * DM + n0 + c0);
    tile[c0 + 0][rr] = f2b(v.x);
    tile[c0 + 1][rr] = f2b(v.y);
    tile[c0 + 2][rr] = f2b(v.z);
    tile[c0 + 3][rr] = f2b(v.w);
  }
  __syncthreads();
  int cc0 = (t & 7) * 8, rn = t >> 3;
  #pragma unroll
  for (int p = 0; p < 2; ++p) {
    int nn = rn + p * 32;
    *(short8*)(Wt + (n0 + nn) * DM + k0 + cc0) = *(const short8*)(&tile[nn][cc0]);
  }
}

// ---- QKV GEMM: 128x128 tile, 4 waves, BK=32 dbuf + vmcnt(4) prefetch (R9) ----
__global__ __launch_bounds__(256) void gemm_qkv_kernel(
    const unsigned short* __restrict__ xb,
    const unsigned short* __restrict__ wqt, const unsigned short* __restrict__ wkt,
    const unsigned short* __restrict__ wvt,
    const float* __restrict__ bq, const float* __restrict__ bk, const float* __restrict__ bv,
    unsigned short* __restrict__ qb, unsigned short* __restrict__ kbuf,
    unsigned short* __restrict__ vt) {
  __shared__ __align__(16) unsigned short smem[18432];
  const unsigned short* Bt; const float* bias; float scale; int zid = blockIdx.z;
  if (zid == 0)      { Bt = wqt; bias = bq; scale = 0.125f * L2E; }
  else if (zid == 1) { Bt = wkt; bias = bk; scale = 1.0f; }
  else               { Bt = wvt; bias = bv; scale = 1.0f; }
  int m0 = blockIdx.x * 128, n0 = blockIdx.y * 128;
  int t = threadIdx.x, w = t >> 6, lane = t & 63, cl = lane & 15, quad = lane >> 4;
  int wr = (w >> 1) * 64, wc = (w & 1) * 64;
  floatx4 acc[4][4];
  #pragma unroll
  for (int i = 0; i < 4; ++i)
    #pragma unroll
    for (int j = 0; j < 4; ++j)
      acc[i][j] = floatx4{0.f, 0.f, 0.f, 0.f};

  auto stage = [&](int kc, int buf) {
    #pragma unroll
    for (int i = 0; i < 2; ++i) {
      int c = i * 256 + t;
      int row = c >> 2, col = (c & 3) ^ (row & 3);
      async16(xb + (m0 + row) * DM + kc * 32 + col * 8, &smem[buf * 4096 + c * 8]);
      async16(Bt + (n0 + row) * DM + kc * 32 + col * 8, &smem[8192 + buf * 4096 + c * 8]);
    }
  };
  stage(0, 0);
  stage(1, 1);

  for (int kc = 0; kc < DM / 32; ++kc) {
    int cur = kc & 1;
    if (kc < DM / 32 - 1) asm volatile("s_waitcnt vmcnt(4)" ::: "memory");
    else                  asm volatile("s_waitcnt vmcnt(0)" ::: "memory");
    BAR();
    const unsigned short* Ac = &smem[cur * 4096];
    const unsigned short* Bc = &smem[8192 + cur * 4096];
    short8 a[4], b[4];
    #pragma unroll
    for (int i = 0; i < 4; ++i)
      a[i] = *(const short8*)&Ac[(wr + i * 16 + cl) * 32 + ((quad ^ (cl & 3)) * 8)];
    #pragma unroll
    for (int j = 0; j < 4; ++j)
      b[j] = *(const short8*)&Bc[(wc + j * 16 + cl) * 32 + ((quad ^ (cl & 3)) * 8)];
    #pragma unroll
    for (int i = 0; i < 4; ++i)
      #pragma unroll
      for (int j = 0; j < 4; ++j)
        acc[i][j] = mfma16(a[i], b[j], acc[i][j]);
    BAR();
    if (kc + 2 < DM / 32) stage(kc + 2, cur);
  }
  __syncthreads();

  int h = (n0 + wc) >> 6;
  if (zid < 2) {
    unsigned short* dst = (zid == 0) ? qb : kbuf;
    #pragma unroll
    for (int j = 0; j < 4; ++j) {
      float bj = bias[n0 + wc + j * 16 + cl];
      int kd = j * 16 + cl;
      #pragma unroll
      for (int i = 0; i < 4; ++i)
        #pragma unroll
        for (int r = 0; r < 4; ++r) {
          int token = m0 + wr + i * 16 + quad * 4 + r;
          int bz = token >> 11, s = token & (SS - 1);
          float val = (acc[i][j][r] + bj) * scale;
          dst[(((bz * NH + h) * SS + s) << 6) + kd] = f2b(val);
        }
    }
  } else {
    unsigned short* tr = &smem[w * 4608];
    #pragma unroll
    for (int j = 0; j < 4; ++j) {
      float bj = bias[n0 + wc + j * 16 + cl];
      #pragma unroll
      for (int i = 0; i < 4; ++i) {
        unsigned short b0 = f2b(acc[i][j][0] + bj), b1 = f2b(acc[i][j][1] + bj);
        unsigned short b2 = f2b(acc[i][j][2] + bj), b3 = f2b(acc[i][j][3] + bj);
        uint2 pk;
        pk.x = (unsigned)b0 | ((unsigned)b1 << 16);
        pk.y = (unsigned)b2 | ((unsigned)b3 << 16);
        *(uint2*)&tr[(j * 16 + cl) * 72 + i * 16 + quad * 4] = pk;
      }
    }
    asm volatile("s_waitcnt lgkmcnt(0)" ::: "memory");
    int tokbase = m0 + wr;
    int bz = tokbase >> 11, s0 = tokbase & (SS - 1);
    unsigned short* vdst = vt + (((bz * NH + h) * KS) * SS) + s0;
    #pragma unroll
    for (int p = 0; p < 8; ++p) {
      int row = p * 8 + (lane >> 3);
      int tk = (lane & 7) * 8;
      short8 vv = *(const short8*)&tr[row * 72 + tk];
      *(short8*)(vdst + row * SS + tk) = vv;
    }
  }
}

// ---- attention: 4 waves x 32 q-rows, S^T/O^T, dbuf K/V shared by WG, vmcnt(4) ----
// Two Q B-fragments per wave (qt=0,1): K/V LDS reads amortized over 2x MFMA work.
// l via ones-MFMA on the same P^T fragments (consistent by construction).
__global__ __launch_bounds__(256) void attn_kernel(
    const unsigned short* __restrict__ Q, const unsigned short* __restrict__ Kb,
    const unsigned short* __restrict__ Vt, unsigned short* __restrict__ AO) {
  __shared__ __align__(16) unsigned short Ks[2][4096], Vs[2][4096]; // 64x64 swizzled dbuf (32 KB)
  __shared__ __align__(16) unsigned short Ps[4][2048];              // per-wave P^T, 2 qt (16 KB)
  int t = threadIdx.x, w = t >> 6, lane = t & 63, cl = lane & 15, quad = lane >> 4;
  int clm = cl & 7;
  int h = blockIdx.y, bz = blockIdx.z, bh = bz * NH + h;
  int q0 = blockIdx.x * 128 + w * 32;
  const unsigned short* Qp = Q + (bh * SS + q0) * KS;
  const unsigned short* Kp = Kb + bh * SS * KS;
  const unsigned short* Vp = Vt + bh * KS * SS;
  unsigned short* p_w = Ps[w];

  short8 qa[2][2];
  #pragma unroll
  for (int qt = 0; qt < 2; ++qt)
    #pragma unroll
    for (int c = 0; c < 2; ++c)
      qa[qt][c] = *(const short8*)(Qp + (qt * 16 + cl) * KS + c * 32 + quad * 8);

  short8 ones;
  #pragma unroll
  for (int j = 0; j < 8; ++j) ones[j] = (short)0x3f80; // bf16 1.0

  floatx4 lacc[2];
  floatx4 oa[2][4];
  #pragma unroll
  for (int qt = 0; qt < 2; ++qt) {
    lacc[qt] = floatx4{0.f, 0.f, 0.f, 0.f};
    #pragma unroll
    for (int j = 0; j < 4; ++j) oa[qt][j] = floatx4{0.f, 0.f, 0.f, 0.f};
  }

  // stage one 64-key tile: 2 K-segments + 2 V-segments per thread (4 vm ops)
  auto stage = [&](int tile, int buf) {
    #pragma unroll
    for (int i = 0; i < 2; ++i) {
      int c = i * 256 + t;
      int row = c >> 3, col8 = (c & 7) ^ (row & 7);
      async16(Kp + (tile * 64 + row) * KS + col8 * 8, &Ks[buf][c * 8]);
    }
    #pragma unroll
    for (int i = 0; i < 2; ++i) {
      int c = i * 256 + t;
      int d = c >> 3, col8 = (c & 7) ^ (d & 7);
      async16(Vp + d * SS + tile * 64 + col8 * 8, &Vs[buf][c * 8]);
    }
  };
  stage(0, 0);
  stage(1, 1);

  const int NTILES = SS / 64;
  for (int it = 0; it < NTILES; ++it) {
    int cur = it & 1;
    if (it < NTILES - 1) asm volatile("s_waitcnt vmcnt(4)" ::: "memory");
    else                 asm volatile("s_waitcnt vmcnt(0)" ::: "memory");
    BAR();

    // S^T: read each K fragment once, feed both qt streams
    floatx4 s[2][4];
    #pragma unroll
    for (int kt = 0; kt < 4; ++kt) {
      short8 kb0 = *(const short8*)&Ks[cur][(kt * 16 + cl) * 64 + ((quad ^ clm) * 8)];
      short8 kb1 = *(const short8*)&Ks[cur][(kt * 16 + cl) * 64 + (((4 + quad) ^ clm) * 8)];
      #pragma unroll
      for (int qt = 0; qt < 2; ++qt) {
        floatx4 z = {0.f, 0.f, 0.f, 0.f};
        s[qt][kt] = mfma16(kb1, qa[qt][1], mfma16(kb0, qa[qt][0], z));
      }
    }
    #pragma unroll
    for (int qt = 0; qt < 2; ++qt)
      #pragma unroll
      for (int kt = 0; kt < 4; ++kt) {
        unsigned u[4];
        #pragma unroll
        for (int r = 0; r < 4; ++r)
          u[r] = __builtin_bit_cast(unsigned, __builtin_amdgcn_exp2f(s[qt][kt][r]));
        uint2 pk;
        pk.x = __builtin_amdgcn_perm(u[1], u[0], 0x07060302);
        pk.y = __builtin_amdgcn_perm(u[3], u[2], 0x07060302);
        int off = qt * 1024 + cl * 64 + (((kt * 2 + (quad >> 1)) ^ clm) * 8) + (quad & 1) * 4;
        *(uint2*)(p_w + off) = pk;
      }
    asm volatile("s_waitcnt lgkmcnt(0)" ::: "memory");
    short8 pa[2][2];
    #pragma unroll
    for (int qt = 0; qt < 2; ++qt) {
      #pragma unroll
      for (int c = 0; c < 2; ++c)
        pa[qt][c] = *(const short8*)(p_w + qt * 1024 + cl * 64 + (((c * 4 + quad) ^ clm) * 8));
      lacc[qt] = mfma16(ones, pa[qt][1], mfma16(ones, pa[qt][0], lacc[qt]));
    }
    // O^T: read each V fragment once, feed both qt streams
    #pragma unroll
    for (int j = 0; j < 4; ++j) {
      short8 vb0 = *(const short8*)&Vs[cur][(j * 16 + cl) * 64 + ((quad ^ clm) * 8)];
      short8 vb1 = *(const short8*)&Vs[cur][(j * 16 + cl) * 64 + (((4 + quad) ^ clm) * 8)];
      #pragma unroll
      for (int qt = 0; qt < 2; ++qt)
        oa[qt][j] = mfma16(vb1, pa[qt][1], mfma16(vb0, pa[qt][0], oa[qt][j]));
    }
    BAR();
    if (it + 2 < NTILES) stage(it + 2, cur);
  }

  #pragma unroll
  for (int qt = 0; qt < 2; ++qt) {
    float inv = 1.0f / lacc[qt][0];
    unsigned short* aop = AO + (bz * SS + q0 + qt * 16 + cl) * DM + h * KS + quad * 4;
    #pragma unroll
    for (int j = 0; j < 4; ++j) {
      unsigned short b0 = f2b(oa[qt][j][0] * inv), b1 = f2b(oa[qt][j][1] * inv);
      unsigned short b2 = f2b(oa[qt][j][2] * inv), b3 = f2b(oa[qt][j][3] * inv);
      uint2 pk;
      pk.x = (unsigned)b0 | ((unsigned)b1 << 16);
      pk.y = (unsigned)b2 | ((unsigned)b3 << 16);
      *(uint2*)(aop + j * 16) = pk;
    }
  }
}

// ---- output GEMM: 256x64 tile, 4 waves, BK=32 dbuf + vmcnt(5) (R9) ----
__global__ __launch_bounds__(256) void gemm_out_kernel(
    const unsigned short* __restrict__ ao, const unsigned short* __restrict__ wot,
    const float* __restrict__ bo, float* __restrict__ out) {
  __shared__ __align__(16) unsigned short As[2][8192], Bs[2][2048]; // 40 KB
  int m0 = blockIdx.x * 256, n0 = blockIdx.y * 64;
  int t = threadIdx.x, w = t >> 6, lane = t & 63, cl = lane & 15, quad = lane >> 4;
  int wr = w * 64;
  floatx4 acc[4][4];
  #pragma unroll
  for (int i = 0; i < 4; ++i)
    #pragma unroll
    for (int j = 0; j < 4; ++j)
      acc[i][j] = floatx4{0.f, 0.f, 0.f, 0.f};

  auto stage = [&](int kc, int buf) {
    #pragma unroll
    for (int i = 0; i < 4; ++i) {
      int c = i * 256 + t;
      int row = c >> 2, col = (c & 3) ^ (row & 3);
      async16(ao + (m0 + row) * HKD + kc * 32 + col * 8, &As[buf][c * 8]);
    }
    {
      int c = t;
      int row = c >> 2, col = (c & 3) ^ (row & 3);
      async16(wot + (n0 + row) * HKD + kc * 32 + col * 8, &Bs[buf][c * 8]);
    }
  };
  stage(0, 0);
  stage(1, 1);

  for (int kc = 0; kc < HKD / 32; ++kc) {
    int cur = kc & 1;
    if (kc < HKD / 32 - 1) asm volatile("s_waitcnt vmcnt(5)" ::: "memory");
    else                   asm volatile("s_waitcnt vmcnt(0)" ::: "memory");
    BAR();
    short8 a[4], b[4];
    #pragma unroll
    for (int i = 0; i < 4; ++i)
      a[i] = *(const short8*)&As[cur][(wr + i * 16 + cl) * 32 + ((quad ^ (cl & 3)) * 8)];
    #pragma unroll
    for (int j = 0; j < 4; ++j)
      b[j] = *(const short8*)&Bs[cur][(j * 16 + cl) * 32 + ((quad ^ (cl & 3)) * 8)];
    #pragma unroll
    for (int i = 0; i < 4; ++i)
      #pragma unroll
      for (int j = 0; j < 4; ++j)
        acc[i][j] = mfma16(a[i], b[j], acc[i][j]);
    BAR();
    if (kc + 2 < HKD / 32) stage(kc + 2, cur);
  }
  #pragma unroll
  for (int j = 0; j < 4; ++j) {
    float bj = bo[n0 + j * 16 + cl];
    #pragma unroll
    for (int i = 0; i < 4; ++i)
      #pragma unroll
      for (int r = 0; r < 4; ++r) {
        int token = m0 + wr + i * 16 + quad * 4 + r;
        out[token * DM + n0 + j * 16 + cl] = acc[i][j][r] + bj;
      }
  }
}

extern "C" void kernel_launch(void* const* d_in, const int* in_sizes, int n_in,
                              void* d_out, int out_size, void* d_ws, size_t ws_size,
                              hipStream_t stream) {
  const float* x  = (const float*)d_in[0];
  const float* Wq = (const float*)d_in[1];
  const float* bq = (const float*)d_in[2];
  const float* Wk = (const float*)d_in[3];
  const float* bk = (const float*)d_in[4];
  const float* Wv = (const float*)d_in[5];
  const float* bv = (const float*)d_in[6];
  const float* Wo = (const float*)d_in[7];
  const float* bo = (const float*)d_in[8];
  float* out = (float*)d_out;
  char* ws = (char*)d_ws;
  unsigned short* xb  = (unsigned short*)(ws);                       // 8 MiB
  unsigned short* wqt = (unsigned short*)(ws + (8ull  << 20));       // 2 MiB
  unsigned short* wkt = (unsigned short*)(ws + (10ull << 20));       // 2 MiB
  unsigned short* wvt = (unsigned short*)(ws + (12ull << 20));       // 2 MiB
  unsigned short* wot = (unsigned short*)(ws + (14ull << 20));       // 2 MiB
  unsigned short* qb  = (unsigned short*)(ws + (16ull << 20));       // 8 MiB
  unsigned short* kbf = (unsigned short*)(ws + (24ull << 20));       // 8 MiB
  unsigned short* vt  = (unsigned short*)(ws + (40ull << 20));       // 8 MiB
  unsigned short* ao  = (unsigned short*)(ws + (48ull << 20));       // 8 MiB

  hipLaunchKernelGGL(prep_kernel, dim3(NT * DM / 1024 + 1024), dim3(256), 0, stream,
                     x, Wq, Wk, Wv, Wo, xb, wqt, wkt, wvt, wot);
  hipLaunchKernelGGL(gemm_qkv_kernel, dim3(NT / 128, HKD / 128, 3), dim3(256), 0, stream,
                     xb, wqt, wkt, wvt, bq, bk, bv, qb, kbf, vt);
  hipLaunchKernelGGL(attn_kernel, dim3(SS / 128, NH, BB), dim3(256), 0, stream, qb, kbf, vt, ao);
  hipLaunchKernelGGL(gemm_out_kernel, dim3(NT / 256, DM / 64), dim3(256), 0, stream, ao, wot, bo, out);
}

// Round 12
// 197.678 us; speedup vs baseline: 1.0783x; 1.0230x over previous
//
#include <hip/hip_runtime.h>

// MHA forward, B=2, S=2048, D=1024, H=16, K=64, fp32 in/out, bf16 MFMA internally.
// R12: attention = split-K-2 dual-stream: 8 waves/WG, waves 0-3 keys [0,1024),
// waves 4-7 keys [1024,2048), each wave 32 q-rows (2 qt fragments; K/V read once,
// fed to both). Two 32-key K/V tile streams DMA-staged concurrently, dbuf+vmcnt(2),
// R9 2-barrier loop. 48 KB LDS -> 2 WG/CU = 16 waves/CU (R9 occupancy) with ~45%
// less LDS read traffic per q-row. Linear partial combine via LDS. GEMMs = R9.

#define NH 16
#define KS 64
#define DM 1024
#define BB 2
#define SS 2048
#define NT (BB*SS)   // 4096 tokens
#define HKD 1024     // NH*KS
#define L2E 1.44269504088896340736f

typedef __attribute__((ext_vector_type(4))) float floatx4;
typedef __attribute__((ext_vector_type(8))) short short8;

#define BAR() asm volatile("s_barrier" ::: "memory")

__device__ __forceinline__ unsigned short f2b(float f) {
  unsigned u = __builtin_bit_cast(unsigned, f);
  u = (u + 0x7fffu + ((u >> 16) & 1u)) >> 16;
  return (unsigned short)u;
}

__device__ __forceinline__ floatx4 mfma16(short8 a, short8 b, floatx4 c) {
  return __builtin_amdgcn_mfma_f32_16x16x32_bf16(a, b, c, 0, 0, 0);
}

// async global->LDS, 16B per lane. LDS dest must be wave-uniform base + lane*16.
__device__ __forceinline__ void async16(const void* g, void* l) {
  __builtin_amdgcn_global_load_lds(
      (const __attribute__((address_space(1))) unsigned int*)g,
      (__attribute__((address_space(3))) unsigned int*)l, 16, 0, 0);
}

// ------ prep: cast x (f32->bf16) + transpose+cast all W, one launch ------
__global__ __launch_bounds__(256) void prep_kernel(
    const float* __restrict__ x,
    const float* __restrict__ Wq, const float* __restrict__ Wk,
    const float* __restrict__ Wv, const float* __restrict__ Wo,
    unsigned short* __restrict__ xb,
    unsigned short* __restrict__ wqt, unsigned short* __restrict__ wkt,
    unsigned short* __restrict__ wvt, unsigned short* __restrict__ wot) {
  int bid = blockIdx.x;
  if (bid < NT * DM / 1024) {
    int i = (bid * 256 + threadIdx.x) * 4;
    float4 v = *(const float4*)(x + i);
    ushort4 o;
    o.x = f2b(v.x); o.y = f2b(v.y); o.z = f2b(v.z); o.w = f2b(v.w);
    *(ushort4*)(xb + i) = o;
    return;
  }
  int b2 = bid - NT * DM / 1024;
  int z = b2 >> 8;
  const float* W; unsigned short* Wt;
  if (z == 0)      { W = Wq; Wt = wqt; }
  else if (z == 1) { W = Wk; Wt = wkt; }
  else if (z == 2) { W = Wv; Wt = wvt; }
  else             { W = Wo; Wt = wot; }
  __shared__ __align__(16) unsigned short tile[64][80];
  int k0 = (b2 & 15) * 64, n0 = ((b2 >> 4) & 15) * 64;
  int t = threadIdx.x;
  int c0 = (t & 15) * 4, r = t >> 4;
  #pragma unroll
  for (int p = 0; p < 4; ++p) {
    int rr = r + p * 16;
    float4 v = *(const float4*)(W + (k0 + rr) * DM + n0 + c0);
    tile[c0 + 0][rr] = f2b(v.x);
    tile[c0 + 1][rr] = f2b(v.y);
    tile[c0 + 2][rr] = f2b(v.z);
    tile[c0 + 3][rr] = f2b(v.w);
  }
  __syncthreads();
  int cc0 = (t & 7) * 8, rn = t >> 3;
  #pragma unroll
  for (int p = 0; p < 2; ++p) {
    int nn = rn + p * 32;
    *(short8*)(Wt + (n0 + nn) * DM + k0 + cc0) = *(const short8*)(&tile[nn][cc0]);
  }
}

// ---- QKV GEMM: 128x128 tile, 4 waves, BK=32 dbuf + vmcnt(4) prefetch (R9) ----
__global__ __launch_bounds__(256) void gemm_qkv_kernel(
    const unsigned short* __restrict__ xb,
    const unsigned short* __restrict__ wqt, const unsigned short* __restrict__ wkt,
    const unsigned short* __restrict__ wvt,
    const float* __restrict__ bq, const float* __restrict__ bk, const float* __restrict__ bv,
    unsigned short* __restrict__ qb, unsigned short* __restrict__ kbuf,
    unsigned short* __restrict__ vt) {
  __shared__ __align__(16) unsigned short smem[18432];
  const unsigned short* Bt; const float* bias; float scale; int zid = blockIdx.z;
  if (zid == 0)      { Bt = wqt; bias = bq; scale = 0.125f * L2E; }
  else if (zid == 1) { Bt = wkt; bias = bk; scale = 1.0f; }
  else               { Bt = wvt; bias = bv; scale = 1.0f; }
  int m0 = blockIdx.x * 128, n0 = blockIdx.y * 128;
  int t = threadIdx.x, w = t >> 6, lane = t & 63, cl = lane & 15, quad = lane >> 4;
  int wr = (w >> 1) * 64, wc = (w & 1) * 64;
  floatx4 acc[4][4];
  #pragma unroll
  for (int i = 0; i < 4; ++i)
    #pragma unroll
    for (int j = 0; j < 4; ++j)
      acc[i][j] = floatx4{0.f, 0.f, 0.f, 0.f};

  auto stage = [&](int kc, int buf) {
    #pragma unroll
    for (int i = 0; i < 2; ++i) {
      int c = i * 256 + t;
      int row = c >> 2, col = (c & 3) ^ (row & 3);
      async16(xb + (m0 + row) * DM + kc * 32 + col * 8, &smem[buf * 4096 + c * 8]);
      async16(Bt + (n0 + row) * DM + kc * 32 + col * 8, &smem[8192 + buf * 4096 + c * 8]);
    }
  };
  stage(0, 0);
  stage(1, 1);

  for (int kc = 0; kc < DM / 32; ++kc) {
    int cur = kc & 1;
    if (kc < DM / 32 - 1) asm volatile("s_waitcnt vmcnt(4)" ::: "memory");
    else                  asm volatile("s_waitcnt vmcnt(0)" ::: "memory");
    BAR();
    const unsigned short* Ac = &smem[cur * 4096];
    const unsigned short* Bc = &smem[8192 + cur * 4096];
    short8 a[4], b[4];
    #pragma unroll
    for (int i = 0; i < 4; ++i)
      a[i] = *(const short8*)&Ac[(wr + i * 16 + cl) * 32 + ((quad ^ (cl & 3)) * 8)];
    #pragma unroll
    for (int j = 0; j < 4; ++j)
      b[j] = *(const short8*)&Bc[(wc + j * 16 + cl) * 32 + ((quad ^ (cl & 3)) * 8)];
    #pragma unroll
    for (int i = 0; i < 4; ++i)
      #pragma unroll
      for (int j = 0; j < 4; ++j)
        acc[i][j] = mfma16(a[i], b[j], acc[i][j]);
    BAR();
    if (kc + 2 < DM / 32) stage(kc + 2, cur);
  }
  __syncthreads();

  int h = (n0 + wc) >> 6;
  if (zid < 2) {
    unsigned short* dst = (zid == 0) ? qb : kbuf;
    #pragma unroll
    for (int j = 0; j < 4; ++j) {
      float bj = bias[n0 + wc + j * 16 + cl];
      int kd = j * 16 + cl;
      #pragma unroll
      for (int i = 0; i < 4; ++i)
        #pragma unroll
        for (int r = 0; r < 4; ++r) {
          int token = m0 + wr + i * 16 + quad * 4 + r;
          int bz = token >> 11, s = token & (SS - 1);
          float val = (acc[i][j][r] + bj) * scale;
          dst[(((bz * NH + h) * SS + s) << 6) + kd] = f2b(val);
        }
    }
  } else {
    unsigned short* tr = &smem[w * 4608];
    #pragma unroll
    for (int j = 0; j < 4; ++j) {
      float bj = bias[n0 + wc + j * 16 + cl];
      #pragma unroll
      for (int i = 0; i < 4; ++i) {
        unsigned short b0 = f2b(acc[i][j][0] + bj), b1 = f2b(acc[i][j][1] + bj);
        unsigned short b2 = f2b(acc[i][j][2] + bj), b3 = f2b(acc[i][j][3] + bj);
        uint2 pk;
        pk.x = (unsigned)b0 | ((unsigned)b1 << 16);
        pk.y = (unsigned)b2 | ((unsigned)b3 << 16);
        *(uint2*)&tr[(j * 16 + cl) * 72 + i * 16 + quad * 4] = pk;
      }
    }
    asm volatile("s_waitcnt lgkmcnt(0)" ::: "memory");
    int tokbase = m0 + wr;
    int bz = tokbase >> 11, s0 = tokbase & (SS - 1);
    unsigned short* vdst = vt + (((bz * NH + h) * KS) * SS) + s0;
    #pragma unroll
    for (int p = 0; p < 8; ++p) {
      int row = p * 8 + (lane >> 3);
      int tk = (lane & 7) * 8;
      short8 vv = *(const short8*)&tr[row * 72 + tk];
      *(short8*)(vdst + row * SS + tk) = vv;
    }
  }
}

// ---- attention: split-K-2 dual-stream, 8 waves x 32 q-rows, 32-key tiles ----
// smem layout (shorts): K tiles [ (st*2+buf)*2048 ], V tiles [8192 + (st*2+buf)*2048],
// P per wave [16384 + w*1024]. 48 KB. Reduction reuses whole smem as floats.
__global__ __launch_bounds__(512) void attn_kernel(
    const unsigned short* __restrict__ Q, const unsigned short* __restrict__ Kb,
    const unsigned short* __restrict__ Vt, unsigned short* __restrict__ AO) {
  __shared__ __align__(16) unsigned short smem[24576];
  int t = threadIdx.x, w = t >> 6, lane = t & 63, cl = lane & 15, quad = lane >> 4;
  int clm = cl & 7, cl3 = cl & 3, cl2 = cl >> 2;
  int h = blockIdx.y, bz = blockIdx.z, bh = bz * NH + h;
  int slice = w & 3, part = w >> 2;
  int q0 = blockIdx.x * 128 + slice * 32;
  const unsigned short* Qp = Q + (bh * SS + q0) * KS;
  const unsigned short* Kp = Kb + bh * SS * KS;
  const unsigned short* Vp = Vt + bh * KS * SS;
  unsigned short* p_w = smem + 16384 + w * 1024;

  short8 qa[2][2];
  #pragma unroll
  for (int qt = 0; qt < 2; ++qt)
    #pragma unroll
    for (int c = 0; c < 2; ++c)
      qa[qt][c] = *(const short8*)(Qp + (qt * 16 + cl) * KS + c * 32 + quad * 8);

  short8 ones;
  #pragma unroll
  for (int j = 0; j < 8; ++j) ones[j] = (short)0x3f80; // bf16 1.0

  floatx4 lacc[2];
  floatx4 oa[2][4];
  #pragma unroll
  for (int qt = 0; qt < 2; ++qt) {
    lacc[qt] = floatx4{0.f, 0.f, 0.f, 0.f};
    #pragma unroll
    for (int j = 0; j < 4; ++j) oa[qt][j] = floatx4{0.f, 0.f, 0.f, 0.f};
  }

  // staging: thread's stream st = t>>8 (waves 0-3 -> stream0, 4-7 -> stream1)
  int st = t >> 8, lt = t & 255;
  int krow = lt >> 3, kcol = (lt & 7) ^ (krow & 7);
  int vd = lt >> 2, vcol = ((lt & 3) ^ (vd & 3) ^ ((vd >> 2) & 3)) & 3;
  auto stage = [&](int it, int buf) {
    async16(Kp + (st * 1024 + it * 32 + krow) * KS + kcol * 8,
            &smem[(st * 2 + buf) * 2048 + lt * 8]);
    async16(Vp + vd * SS + st * 1024 + it * 32 + vcol * 8,
            &smem[8192 + (st * 2 + buf) * 2048 + lt * 8]);
  };
  stage(0, 0);
  stage(1, 1);

  const int NIT = 1024 / 32; // 32 tiles per part
  for (int it = 0; it < NIT; ++it) {
    int cur = it & 1;
    if (it < NIT - 1) asm volatile("s_waitcnt vmcnt(2)" ::: "memory");
    else              asm volatile("s_waitcnt vmcnt(0)" ::: "memory");
    BAR();
    const unsigned short* Kc = &smem[(part * 2 + cur) * 2048];
    const unsigned short* Vc = &smem[8192 + (part * 2 + cur) * 2048];

    // S^T: kt = 0,1 (32 keys); K fragments read once, feed both qt
    floatx4 s[2][2];
    #pragma unroll
    for (int kt = 0; kt < 2; ++kt) {
      short8 kb0 = *(const short8*)&Kc[(kt * 16 + cl) * 64 + ((quad ^ clm) * 8)];
      short8 kb1 = *(const short8*)&Kc[(kt * 16 + cl) * 64 + (((4 + quad) ^ clm) * 8)];
      #pragma unroll
      for (int qt = 0; qt < 2; ++qt) {
        floatx4 z = {0.f, 0.f, 0.f, 0.f};
        s[qt][kt] = mfma16(kb1, qa[qt][1], mfma16(kb0, qa[qt][0], z));
      }
    }
    // exp2 + perm-pack -> P^T (rows q=cl, 32 t, 4 blocks XOR-swizzled)
    #pragma unroll
    for (int qt = 0; qt < 2; ++qt)
      #pragma unroll
      for (int kt = 0; kt < 2; ++kt) {
        unsigned u[4];
        #pragma unroll
        for (int r = 0; r < 4; ++r)
          u[r] = __builtin_bit_cast(unsigned, __builtin_amdgcn_exp2f(s[qt][kt][r]));
        uint2 pk;
        pk.x = __builtin_amdgcn_perm(u[1], u[0], 0x07060302);
        pk.y = __builtin_amdgcn_perm(u[3], u[2], 0x07060302);
        int blk = ((kt * 2 + (quad >> 1)) ^ cl3 ^ cl2) & 3;
        int off = qt * 512 + cl * 32 + blk * 8 + (quad & 1) * 4;
        *(uint2*)(p_w + off) = pk;
      }
    asm volatile("s_waitcnt lgkmcnt(0)" ::: "memory");
    short8 pa[2];
    #pragma unroll
    for (int qt = 0; qt < 2; ++qt) {
      pa[qt] = *(const short8*)(p_w + qt * 512 + cl * 32 + (((quad ^ cl3 ^ cl2) & 3) * 8));
      lacc[qt] = mfma16(ones, pa[qt], lacc[qt]);
    }
    // O^T: V fragments read once, feed both qt
    #pragma unroll
    for (int j = 0; j < 4; ++j) {
      short8 vb = *(const short8*)&Vc[(j * 16 + cl) * 32 + (((quad ^ cl3 ^ cl2) & 3) * 8)];
      #pragma unroll
      for (int qt = 0; qt < 2; ++qt)
        oa[qt][j] = mfma16(vb, pa[qt], oa[qt][j]);
    }
    BAR();
    if (it + 2 < NIT) stage(it + 2, cur);
  }

  // combine parts: part1 dumps (O, l) to LDS; part0 adds, normalizes, stores
  __syncthreads();
  float* red = (float*)smem;
  float* base = red + slice * 2304; // 4 slices x 9216B <= 48KB
  if (part == 1) {
    #pragma unroll
    for (int qt = 0; qt < 2; ++qt)
      #pragma unroll
      for (int j = 0; j < 4; ++j)
        *(floatx4*)(base + (((qt * 4 + j) * 64 + lane) << 2)) = oa[qt][j];
    base[2048 + lane * 2 + 0] = lacc[0][0];
    base[2048 + lane * 2 + 1] = lacc[1][0];
  }
  __syncthreads();
  if (part == 0) {
    #pragma unroll
    for (int qt = 0; qt < 2; ++qt)
      #pragma unroll
      for (int j = 0; j < 4; ++j)
        oa[qt][j] += *(const floatx4*)(base + (((qt * 4 + j) * 64 + lane) << 2));
    float lsum[2];
    lsum[0] = lacc[0][0] + base[2048 + lane * 2 + 0];
    lsum[1] = lacc[1][0] + base[2048 + lane * 2 + 1];
    #pragma unroll
    for (int qt = 0; qt < 2; ++qt) {
      float inv = 1.0f / lsum[qt];
      unsigned short* aop = AO + (bz * SS + q0 + qt * 16 + cl) * DM + h * KS + quad * 4;
      #pragma unroll
      for (int j = 0; j < 4; ++j) {
        unsigned short b0 = f2b(oa[qt][j][0] * inv), b1 = f2b(oa[qt][j][1] * inv);
        unsigned short b2 = f2b(oa[qt][j][2] * inv), b3 = f2b(oa[qt][j][3] * inv);
        uint2 pk;
        pk.x = (unsigned)b0 | ((unsigned)b1 << 16);
        pk.y = (unsigned)b2 | ((unsigned)b3 << 16);
        *(uint2*)(aop + j * 16) = pk;
      }
    }
  }
}

// ---- output GEMM: 256x64 tile, 4 waves, BK=32 dbuf + vmcnt(5) (R9) ----
__global__ __launch_bounds__(256) void gemm_out_kernel(
    const unsigned short* __restrict__ ao, const unsigned short* __restrict__ wot,
    const float* __restrict__ bo, float* __restrict__ out) {
  __shared__ __align__(16) unsigned short As[2][8192], Bs[2][2048]; // 40 KB
  int m0 = blockIdx.x * 256, n0 = blockIdx.y * 64;
  int t = threadIdx.x, w = t >> 6, lane = t & 63, cl = lane & 15, quad = lane >> 4;
  int wr = w * 64;
  floatx4 acc[4][4];
  #pragma unroll
  for (int i = 0; i < 4; ++i)
    #pragma unroll
    for (int j = 0; j < 4; ++j)
      acc[i][j] = floatx4{0.f, 0.f, 0.f, 0.f};

  auto stage = [&](int kc, int buf) {
    #pragma unroll
    for (int i = 0; i < 4; ++i) {
      int c = i * 256 + t;
      int row = c >> 2, col = (c & 3) ^ (row & 3);
      async16(ao + (m0 + row) * HKD + kc * 32 + col * 8, &As[buf][c * 8]);
    }
    {
      int c = t;
      int row = c >> 2, col = (c & 3) ^ (row & 3);
      async16(wot + (n0 + row) * HKD + kc * 32 + col * 8, &Bs[buf][c * 8]);
    }
  };
  stage(0, 0);
  stage(1, 1);

  for (int kc = 0; kc < HKD / 32; ++kc) {
    int cur = kc & 1;
    if (kc < HKD / 32 - 1) asm volatile("s_waitcnt vmcnt(5)" ::: "memory");
    else                   asm volatile("s_waitcnt vmcnt(0)" ::: "memory");
    BAR();
    short8 a[4], b[4];
    #pragma unroll
    for (int i = 0; i < 4; ++i)
      a[i] = *(const short8*)&As[cur][(wr + i * 16 + cl) * 32 + ((quad ^ (cl & 3)) * 8)];
    #pragma unroll
    for (int j = 0; j < 4; ++j)
      b[j] = *(const short8*)&Bs[cur][(j * 16 + cl) * 32 + ((quad ^ (cl & 3)) * 8)];
    #pragma unroll
    for (int i = 0; i < 4; ++i)
      #pragma unroll
      for (int j = 0; j < 4; ++j)
        acc[i][j] = mfma16(a[i], b[j], acc[i][j]);
    BAR();
    if (kc + 2 < HKD / 32) stage(kc + 2, cur);
  }
  #pragma unroll
  for (int j = 0; j < 4; ++j) {
    float bj = bo[n0 + j * 16 + cl];
    #pragma unroll
    for (int i = 0; i < 4; ++i)
      #pragma unroll
      for (int r = 0; r < 4; ++r) {
        int token = m0 + wr + i * 16 + quad * 4 + r;
        out[token * DM + n0 + j * 16 + cl] = acc[i][j][r] + bj;
      }
  }
}

extern "C" void kernel_launch(void* const* d_in, const int* in_sizes, int n_in,
                              void* d_out, int out_size, void* d_ws, size_t ws_size,
                              hipStream_t stream) {
  const float* x  = (const float*)d_in[0];
  const float* Wq = (const float*)d_in[1];
  const float* bq = (const float*)d_in[2];
  const float* Wk = (const float*)d_in[3];
  const float* bk = (const float*)d_in[4];
  const float* Wv = (const float*)d_in[5];
  const float* bv = (const float*)d_in[6];
  const float* Wo = (const float*)d_in[7];
  const float* bo = (const float*)d_in[8];
  float* out = (float*)d_out;
  char* ws = (char*)d_ws;
  unsigned short* xb  = (unsigned short*)(ws);                       // 8 MiB
  unsigned short* wqt = (unsigned short*)(ws + (8ull  << 20));       // 2 MiB
  unsigned short* wkt = (unsigned short*)(ws + (10ull << 20));       // 2 MiB
  unsigned short* wvt = (unsigned short*)(ws + (12ull << 20));       // 2 MiB
  unsigned short* wot = (unsigned short*)(ws + (14ull << 20));       // 2 MiB
  unsigned short* qb  = (unsigned short*)(ws + (16ull << 20));       // 8 MiB
  unsigned short* kbf = (unsigned short*)(ws + (24ull << 20));       // 8 MiB
  unsigned short* vt  = (unsigned short*)(ws + (40ull << 20));       // 8 MiB
  unsigned short* ao  = (unsigned short*)(ws + (48ull << 20));       // 8 MiB

  hipLaunchKernelGGL(prep_kernel, dim3(NT * DM / 1024 + 1024), dim3(256), 0, stream,
                     x, Wq, Wk, Wv, Wo, xb, wqt, wkt, wvt, wot);
  hipLaunchKernelGGL(gemm_qkv_kernel, dim3(NT / 128, HKD / 128, 3), dim3(256), 0, stream,
                     xb, wqt, wkt, wvt, bq, bk, bv, qb, kbf, vt);
  hipLaunchKernelGGL(attn_kernel, dim3(SS / 128, NH, BB), dim3(512), 0, stream, qb, kbf, vt, ao);
  hipLaunchKernelGGL(gemm_out_kernel, dim3(NT / 256, DM / 64), dim3(256), 0, stream, ao, wot, bo, out);
}